// Round 1
// baseline (426.729 us; speedup 1.0000x reference)
//
#include <hip/hip_runtime.h>
#include <hip/hip_bf16.h>

typedef float f32x4 __attribute__((ext_vector_type(4)));
typedef short s16x8 __attribute__((ext_vector_type(8)));
typedef int i32x4 __attribute__((ext_vector_type(4)));
typedef unsigned short u16;

#define BM 128
#define BN 128
#define BK 64

__constant__ float NF4_TBL[16] = {
    -1.0f, -0.6961928009986877f, -0.5250730514526367f, -0.39491748809814453f,
    -0.28444138169288635f, -0.18477343022823334f, -0.09105003625154495f, 0.0f,
    0.07958029955625534f, 0.16093020141124725f, 0.24611230194568634f,
    0.33791524171829224f, 0.44070982933044434f, 0.5626170039176941f,
    0.7229568362236023f, 1.0f};

static __device__ __forceinline__ unsigned short f2bf(float f) {
  unsigned u = __builtin_bit_cast(unsigned, f);
  u += 0x7fffu + ((u >> 16) & 1u);  // RNE
  return (unsigned short)(u >> 16);
}

// Pass 1: dequant NF4 codes -> bf16 W (row-major [N][K]) into workspace.
__global__ __launch_bounds__(256)
void dequant_w(const int* __restrict__ codes, const float* __restrict__ absmax,
               u16* __restrict__ wq, long long total) {
  __shared__ float lut[512];
  for (int j = threadIdx.x; j < 512; j += 256) lut[j] = NF4_TBL[j >> 5];
  __syncthreads();
  const int ln31 = threadIdx.x & 31;
  long long e = ((long long)blockIdx.x * 256 + threadIdx.x) * 8;
  if (e >= total) return;
  i32x4 c0 = *(const i32x4*)(codes + e);
  i32x4 c1 = *(const i32x4*)(codes + e + 4);
  float am = absmax[e >> 6];
  s16x8 o;
#pragma unroll
  for (int j = 0; j < 4; ++j) {
    o[j] = (short)f2bf(lut[(c0[j] << 5) + ln31] * am);
    o[j + 4] = (short)f2bf(lut[(c1[j] << 5) + ln31] * am);
  }
  *(s16x8*)(wq + e) = o;
}

template <bool FUSED>
static __device__ __forceinline__ void stage_load(
    const float* __restrict__ ap0, const int* __restrict__ cp0,
    const u16* __restrict__ wp0, const float* __restrict__ am0, int K, int kt,
    f32x4 (&ar)[4][2], i32x4 (&cr)[4][2], s16x8 (&wreg)[4], float (&amr)[4]) {
  const size_t ko = (size_t)kt * BK;
#pragma unroll
  for (int p = 0; p < 4; ++p) {
    const float* ap = ap0 + (size_t)(p * 32) * K + ko;
    ar[p][0] = *(const f32x4*)ap;
    ar[p][1] = *(const f32x4*)(ap + 4);
    if constexpr (FUSED) {
      const int* cp = cp0 + (size_t)(p * 32) * K + ko;
      cr[p][0] = *(const i32x4*)cp;
      cr[p][1] = *(const i32x4*)(cp + 4);
      amr[p] = am0[p * 32 * (K >> 6) + kt];
    } else {
      wreg[p] = *(const s16x8*)(wp0 + (size_t)(p * 32) * K + ko);
    }
  }
}

// C[M,N] = X[M,K] * W[N,K]^T + bias ;  A,B staged to LDS as bf16 with XOR swizzle.
template <bool FUSED>
__global__ __launch_bounds__(256, 2)
void gemm_nf4(const float* __restrict__ X, const int* __restrict__ CODES,
              const u16* __restrict__ WQ, const float* __restrict__ AMAX,
              const float* __restrict__ BIAS, float* __restrict__ OUT,
              int M, int N, int K) {
  __shared__ short As[BM * BK];
  __shared__ short Bs[BN * BK];
  __shared__ float lut[512];

  const int tid = threadIdx.x;
  const int lane = tid & 63;
  const int wid = tid >> 6;

  if constexpr (FUSED) {
#pragma unroll
    for (int j = 0; j < 2; ++j) {
      int idx = tid + j * 256;
      lut[idx] = NF4_TBL[idx >> 5];
    }
  }

  // XCD-aware bijective block swizzle (grid divisible by 8 here).
  int nwg = (int)gridDim.x;
  int b = (int)blockIdx.x;
  if ((nwg & 7) == 0) b = (b & 7) * (nwg >> 3) + (b >> 3);
  const int ntn = N / BN;
  const int tm = b / ntn;
  const int tn = b % ntn;

  // staging mapping: 4 passes; row = p*32 + tid/8, col = (tid&7)*8 elems
  const int srow = tid >> 3;
  const int scol = (tid & 7) * 8;
  const int ln31 = tid & 31;
  const int swz_w = (srow & 7) << 4;

  const float* ap0 = X + (size_t)(tm * BM + srow) * K + scol;
  const int* cp0 = CODES + (size_t)(tn * BN + srow) * K + scol;
  const u16* wp0 = WQ + (size_t)(tn * BN + srow) * K + scol;
  const float* am0 = AMAX + (size_t)(tn * BN + srow) * (K >> 6);

  f32x4 ar[4][2];
  i32x4 cr[4][2];
  s16x8 wreg[4];
  float amr[4];

  f32x4 acc[4][4];
#pragma unroll
  for (int i = 0; i < 4; ++i)
#pragma unroll
    for (int j = 0; j < 4; ++j) {
      f32x4 z = {0.f, 0.f, 0.f, 0.f};
      acc[i][j] = z;
    }

  const int wr = wid >> 1;
  const int wc = wid & 1;
  const int frow = lane & 15;
  const int fcolb = (lane >> 4) * 16;  // byte offset of k-group
  const int arow = wr * 64 + frow;
  const int brow = wc * 64 + frow;
  const int aswz = (arow & 7) << 4;
  const int bswz = (brow & 7) << 4;
  const char* asp = (const char*)As + arow * 128;
  const char* bsp = (const char*)Bs + brow * 128;
  char* awp = (char*)As + srow * 128 + ((scol * 2) ^ swz_w);
  char* bwp = (char*)Bs + srow * 128 + ((scol * 2) ^ swz_w);

  const int nkt = K / BK;
  stage_load<FUSED>(ap0, cp0, wp0, am0, K, 0, ar, cr, wreg, amr);

  for (int kt = 0; kt < nkt; ++kt) {
    __syncthreads();  // previous tile's LDS reads done (also covers lut init)
    // convert + write staged regs -> LDS
#pragma unroll
    for (int p = 0; p < 4; ++p) {
      s16x8 av;
#pragma unroll
      for (int j = 0; j < 4; ++j) {
        av[j] = (short)f2bf(ar[p][0][j]);
        av[j + 4] = (short)f2bf(ar[p][1][j]);
      }
      *(s16x8*)(awp + p * 32 * 128) = av;
      s16x8 bv;
      if constexpr (FUSED) {
        float am = amr[p];
#pragma unroll
        for (int j = 0; j < 4; ++j) {
          bv[j] = (short)f2bf(lut[(cr[p][0][j] << 5) + ln31] * am);
          bv[j + 4] = (short)f2bf(lut[(cr[p][1][j] << 5) + ln31] * am);
        }
      } else {
        bv = wreg[p];
      }
      *(s16x8*)(bwp + p * 32 * 128) = bv;
    }
    __syncthreads();  // tile visible

    if (kt + 1 < nkt)  // prefetch next tile into regs; overlaps compute below
      stage_load<FUSED>(ap0, cp0, wp0, am0, K, kt + 1, ar, cr, wreg, amr);

#pragma unroll
    for (int kk = 0; kk < 2; ++kk) {
      const int qa = (fcolb | (kk << 6)) ^ aswz;
      const int qb = (fcolb | (kk << 6)) ^ bswz;
      s16x8 af[4], bfr[4];
#pragma unroll
      for (int mi = 0; mi < 4; ++mi)
        af[mi] = *(const s16x8*)(asp + mi * 2048 + qa);
#pragma unroll
      for (int ni = 0; ni < 4; ++ni)
        bfr[ni] = *(const s16x8*)(bsp + ni * 2048 + qb);
#pragma unroll
      for (int mi = 0; mi < 4; ++mi)
#pragma unroll
        for (int ni = 0; ni < 4; ++ni)
          acc[mi][ni] = __builtin_amdgcn_mfma_f32_16x16x32_bf16(
              af[mi], bfr[ni], acc[mi][ni], 0, 0, 0);
    }
  }

  // epilogue: C layout col = lane&15, row = (lane>>4)*4 + j
  const int crow = tm * BM + wr * 64 + ((lane >> 4) << 2);
  const int ccol = tn * BN + wc * 64 + frow;
  float bvv[4];
#pragma unroll
  for (int ni = 0; ni < 4; ++ni) bvv[ni] = BIAS[ccol + ni * 16];
#pragma unroll
  for (int mi = 0; mi < 4; ++mi)
#pragma unroll
    for (int ni = 0; ni < 4; ++ni) {
#pragma unroll
      for (int j = 0; j < 4; ++j) {
        OUT[(size_t)(crow + mi * 16 + j) * N + ccol + ni * 16] =
            acc[mi][ni][j] + bvv[ni];
      }
    }
}

extern "C" void kernel_launch(void* const* d_in, const int* in_sizes, int n_in,
                              void* d_out, int out_size, void* d_ws,
                              size_t ws_size, hipStream_t stream) {
  const float* x = (const float*)d_in[0];
  const int* codes = (const int*)d_in[1];
  const float* absmax = (const float*)d_in[2];
  const float* bias = (const float*)d_in[3];
  float* out = (float*)d_out;

  const int N = in_sizes[3];                 // 4096 (bias length = out features)
  const long long nk = (long long)in_sizes[1];  // N*K
  const int K = (int)(nk / N);               // 4096
  const int M = in_sizes[0] / K;             // 8192

  const size_t wneed = (size_t)nk * sizeof(u16);
  const int nblocks = (M / BM) * (N / BN);
  dim3 grid(nblocks), blk(256);

  if (ws_size >= wneed) {
    u16* wq = (u16*)d_ws;
    int dblocks = (int)((nk / 8 + 255) / 256);
    dequant_w<<<dblocks, 256, 0, stream>>>(codes, absmax, wq, nk);
    gemm_nf4<false><<<grid, blk, 0, stream>>>(x, codes, wq, absmax, bias, out,
                                              M, N, K);
  } else {
    gemm_nf4<true><<<grid, blk, 0, stream>>>(x, codes, (const u16*)nullptr,
                                             absmax, bias, out, M, N, K);
  }
}

// Round 2
// 308.149 us; speedup vs baseline: 1.3848x; 1.3848x over previous
//
#include <hip/hip_runtime.h>
#include <hip/hip_bf16.h>

typedef float f32x4 __attribute__((ext_vector_type(4)));
typedef short s16x8 __attribute__((ext_vector_type(8)));
typedef int i32x4 __attribute__((ext_vector_type(4)));
typedef unsigned short u16;

__constant__ float NF4_TBL[16] = {
    -1.0f, -0.6961928009986877f, -0.5250730514526367f, -0.39491748809814453f,
    -0.28444138169288635f, -0.18477343022823334f, -0.09105003625154495f, 0.0f,
    0.07958029955625534f, 0.16093020141124725f, 0.24611230194568634f,
    0.33791524171829224f, 0.44070982933044434f, 0.5626170039176941f,
    0.7229568362236023f, 1.0f};

static __device__ __forceinline__ unsigned short f2bf(float f) {
  unsigned u = __builtin_bit_cast(unsigned, f);
  u += 0x7fffu + ((u >> 16) & 1u);  // RNE
  return (unsigned short)(u >> 16);
}

static __device__ __forceinline__ void gload16(const void* g, void* l) {
  __builtin_amdgcn_global_load_lds(
      (const __attribute__((address_space(1))) unsigned*)g,
      (__attribute__((address_space(3))) unsigned*)l, 16, 0, 0);
}

// ---------------- prep pass 1: X fp32 -> bf16 ----------------
__global__ __launch_bounds__(256)
void convert_x(const float* __restrict__ x, u16* __restrict__ xb,
               long long total) {
  long long i = ((long long)blockIdx.x * 256 + threadIdx.x) * 8;
  if (i >= total) return;
  f32x4 a = *(const f32x4*)(x + i);
  f32x4 b = *(const f32x4*)(x + i + 4);
  s16x8 o;
#pragma unroll
  for (int j = 0; j < 4; ++j) {
    o[j] = (short)f2bf(a[j]);
    o[j + 4] = (short)f2bf(b[j]);
  }
  *(s16x8*)(xb + i) = o;
}

// ---------------- prep pass 2: NF4 codes -> bf16 W ----------------
__global__ __launch_bounds__(256)
void dequant_w(const int* __restrict__ codes, const float* __restrict__ absmax,
               u16* __restrict__ wq, long long total) {
  __shared__ float lut[512];
  for (int j = threadIdx.x; j < 512; j += 256) lut[j] = NF4_TBL[j >> 5];
  __syncthreads();
  const int ln31 = threadIdx.x & 31;
  long long e = ((long long)blockIdx.x * 256 + threadIdx.x) * 8;
  if (e >= total) return;
  i32x4 c0 = *(const i32x4*)(codes + e);
  i32x4 c1 = *(const i32x4*)(codes + e + 4);
  float am = absmax[e >> 6];
  s16x8 o;
#pragma unroll
  for (int j = 0; j < 4; ++j) {
    o[j] = (short)f2bf(lut[(c0[j] << 5) + ln31] * am);
    o[j + 4] = (short)f2bf(lut[(c1[j] << 5) + ln31] * am);
  }
  *(s16x8*)(wq + e) = o;
}

// ---------------- main: 256x256 bf16 GEMM, BK=32, 4-slot LDS ring ----------
// C[M,N] = A[M,K] * B[N,K]^T + bias
// Pipeline: prefetch distance 3 K-tiles; counted s_waitcnt vmcnt(8) + raw
// s_barrier per iteration (no drain in steady state). global_load_lds with
// pre-swizzled global source; ds_read_b128 with matching XOR swizzle
// (byte ^= ((row>>1)&3)<<4 within 64B rows -> 2-way bank alias = free).
#define TBM 256
#define TBN 256
#define TBK 32
#define SLOT_BYTES 32768  // A 16 KiB + B 16 KiB
#define NSLOT 4

__global__ __launch_bounds__(512, 2)
void gemm8(const u16* __restrict__ A, const u16* __restrict__ B,
           const float* __restrict__ BIAS, float* __restrict__ OUT,
           int M, int N, int K) {
  __shared__ __align__(16) char lds8[NSLOT * SLOT_BYTES];  // 128 KiB

  const int tid = threadIdx.x;
  const int lane = tid & 63;
  const int wid = tid >> 6;
  const int wr = wid >> 2;  // 0..1  (M split)
  const int wc = wid & 3;   // 0..3  (N split)

  int nwg = (int)gridDim.x;
  int b = (int)blockIdx.x;
  if ((nwg & 7) == 0) b = (b & 7) * (nwg >> 3) + (b >> 3);  // XCD swizzle
  const int ntm = M / TBM;
  const int tn = b / ntm;  // column-major tile order: B-panel L2 reuse
  const int tm = b % ntm;

  const long long K2 = (long long)K * 2;  // global row stride (bytes)
  const char* gA = (const char*)A + (long long)tm * TBM * K2;
  const char* gB = (const char*)B + (long long)tn * TBN * K2;

  // staging geometry: per issue, 512 threads x 16B = 8 KiB (128 LDS rows of
  // 64B). thread covers LDS linear p = j*8192 + tid*16.
  const int srow = tid >> 2;            // p>>6 for j=0; j adds 128 rows
  const int scolb = (tid & 3) * 16;     // byte col within 64B row
  const int sswz = ((srow >> 1) & 3) << 4;   // same for row+128
  const int scols = scolb ^ sswz;            // pre-swizzled source col
  const long long sgoff0 = (long long)srow * K2 + scols;
  const long long sgoff1 = (long long)(srow + 128) * K2 + scols;
  const int sldsoff = tid * 16;

  // fragment read addressing
  const int frow = lane & 15;
  const int kb = (lane >> 4) << 4;  // 0,16,32,48 bytes (8 bf16 per k-group)
  const int arow = wr * 128 + frow;
  const int brow = wc * 64 + frow;
  const int aswz = ((arow >> 1) & 3) << 4;  // invariant under row+16
  const int bswz = ((brow >> 1) & 3) << 4;
  const int aoff = arow * 64 + (kb ^ aswz);
  const int boff = 16384 + brow * 64 + (kb ^ bswz);

  f32x4 acc[8][4];
#pragma unroll
  for (int i = 0; i < 8; ++i)
#pragma unroll
    for (int j = 0; j < 4; ++j) {
      f32x4 z = {0.f, 0.f, 0.f, 0.f};
      acc[i][j] = z;
    }

  auto stage = [&](int kt, int slot) {
    char* sb = lds8 + slot * SLOT_BYTES;
    const long long kofs = (long long)kt * (TBK * 2);
    gload16(gA + sgoff0 + kofs, sb + sldsoff);
    gload16(gA + sgoff1 + kofs, sb + 8192 + sldsoff);
    gload16(gB + sgoff0 + kofs, sb + 16384 + sldsoff);
    gload16(gB + sgoff1 + kofs, sb + 16384 + 8192 + sldsoff);
  };

  const int nkt = K / TBK;
  stage(0, 0);
  stage(1, 1);
  stage(2, 2);

  for (int t = 0; t < nkt; ++t) {
    // tile t resident when all but the newest (t+1,t+2) loads retired
    if (t + 2 < nkt)
      asm volatile("s_waitcnt vmcnt(8)" ::: "memory");
    else if (t + 1 < nkt)
      asm volatile("s_waitcnt vmcnt(4)" ::: "memory");
    else
      asm volatile("s_waitcnt vmcnt(0)" ::: "memory");
    __builtin_amdgcn_s_barrier();
    __builtin_amdgcn_sched_barrier(0);

    if (t + 3 < nkt) stage(t + 3, (t + 3) & 3);  // slot (t-1)&3: readers done
    __builtin_amdgcn_sched_barrier(0);

    const char* sb = lds8 + (t & 3) * SLOT_BYTES;
    s16x8 af[8], bfv[4];
#pragma unroll
    for (int mi = 0; mi < 8; ++mi)
      af[mi] = *(const s16x8*)(sb + aoff + mi * 1024);
#pragma unroll
    for (int ni = 0; ni < 4; ++ni)
      bfv[ni] = *(const s16x8*)(sb + boff + ni * 1024);

    __builtin_amdgcn_s_setprio(1);
#pragma unroll
    for (int mi = 0; mi < 8; ++mi)
#pragma unroll
      for (int ni = 0; ni < 4; ++ni)
        acc[mi][ni] = __builtin_amdgcn_mfma_f32_16x16x32_bf16(
            af[mi], bfv[ni], acc[mi][ni], 0, 0, 0);
    __builtin_amdgcn_s_setprio(0);
  }

  // epilogue: D row = (lane>>4)*4 + j (M), col = lane&15 (N)
  const int orow0 = tm * TBM + wr * 128 + ((lane >> 4) << 2);
  const int ocol0 = tn * TBN + wc * 64 + frow;
  float bv[4];
#pragma unroll
  for (int ni = 0; ni < 4; ++ni) bv[ni] = BIAS[ocol0 + ni * 16];
#pragma unroll
  for (int mi = 0; mi < 8; ++mi)
#pragma unroll
    for (int ni = 0; ni < 4; ++ni) {
#pragma unroll
      for (int j = 0; j < 4; ++j) {
        OUT[(long long)(orow0 + mi * 16 + j) * N + ocol0 + ni * 16] =
            acc[mi][ni][j] + bv[ni];
      }
    }
}

// ---------------- fallback: round-1 128x128 reg-staged kernel ----------------
#define BM 128
#define BN 128
#define BK 64

template <bool FUSED>
static __device__ __forceinline__ void stage_load(
    const float* __restrict__ ap0, const int* __restrict__ cp0,
    const u16* __restrict__ wp0, const float* __restrict__ am0, int K, int kt,
    f32x4 (&ar)[4][2], i32x4 (&cr)[4][2], s16x8 (&wreg)[4], float (&amr)[4]) {
  const size_t ko = (size_t)kt * BK;
#pragma unroll
  for (int p = 0; p < 4; ++p) {
    const float* ap = ap0 + (size_t)(p * 32) * K + ko;
    ar[p][0] = *(const f32x4*)ap;
    ar[p][1] = *(const f32x4*)(ap + 4);
    if constexpr (FUSED) {
      const int* cp = cp0 + (size_t)(p * 32) * K + ko;
      cr[p][0] = *(const i32x4*)cp;
      cr[p][1] = *(const i32x4*)(cp + 4);
      amr[p] = am0[p * 32 * (K >> 6) + kt];
    } else {
      wreg[p] = *(const s16x8*)(wp0 + (size_t)(p * 32) * K + ko);
    }
  }
}

template <bool FUSED>
__global__ __launch_bounds__(256, 2)
void gemm_nf4(const float* __restrict__ X, const int* __restrict__ CODES,
              const u16* __restrict__ WQ, const float* __restrict__ AMAX,
              const float* __restrict__ BIAS, float* __restrict__ OUT,
              int M, int N, int K) {
  __shared__ short As[BM * BK];
  __shared__ short Bs[BN * BK];
  __shared__ float lut[512];

  const int tid = threadIdx.x;
  const int lane = tid & 63;
  const int wid = tid >> 6;

  if constexpr (FUSED) {
#pragma unroll
    for (int j = 0; j < 2; ++j) {
      int idx = tid + j * 256;
      lut[idx] = NF4_TBL[idx >> 5];
    }
  }

  int nwg = (int)gridDim.x;
  int b = (int)blockIdx.x;
  if ((nwg & 7) == 0) b = (b & 7) * (nwg >> 3) + (b >> 3);
  const int ntn = N / BN;
  const int tm = b / ntn;
  const int tn = b % ntn;

  const int srow = tid >> 3;
  const int scol = (tid & 7) * 8;
  const int ln31 = tid & 31;
  const int swz_w = (srow & 7) << 4;

  const float* ap0 = X + (size_t)(tm * BM + srow) * K + scol;
  const int* cp0 = CODES + (size_t)(tn * BN + srow) * K + scol;
  const u16* wp0 = WQ + (size_t)(tn * BN + srow) * K + scol;
  const float* am0 = AMAX + (size_t)(tn * BN + srow) * (K >> 6);

  f32x4 ar[4][2];
  i32x4 cr[4][2];
  s16x8 wreg[4];
  float amr[4];

  f32x4 acc[4][4];
#pragma unroll
  for (int i = 0; i < 4; ++i)
#pragma unroll
    for (int j = 0; j < 4; ++j) {
      f32x4 z = {0.f, 0.f, 0.f, 0.f};
      acc[i][j] = z;
    }

  const int wr = wid >> 1;
  const int wc = wid & 1;
  const int frow = lane & 15;
  const int fcolb = (lane >> 4) * 16;
  const int arow = wr * 64 + frow;
  const int brow = wc * 64 + frow;
  const int aswz = (arow & 7) << 4;
  const int bswz = (brow & 7) << 4;
  const char* asp = (const char*)As + arow * 128;
  const char* bsp = (const char*)Bs + brow * 128;
  char* awp = (char*)As + srow * 128 + ((scol * 2) ^ swz_w);
  char* bwp = (char*)Bs + srow * 128 + ((scol * 2) ^ swz_w);

  const int nkt = K / BK;
  stage_load<FUSED>(ap0, cp0, wp0, am0, K, 0, ar, cr, wreg, amr);

  for (int kt = 0; kt < nkt; ++kt) {
    __syncthreads();
#pragma unroll
    for (int p = 0; p < 4; ++p) {
      s16x8 av;
#pragma unroll
      for (int j = 0; j < 4; ++j) {
        av[j] = (short)f2bf(ar[p][0][j]);
        av[j + 4] = (short)f2bf(ar[p][1][j]);
      }
      *(s16x8*)(awp + p * 32 * 128) = av;
      s16x8 bv;
      if constexpr (FUSED) {
        float am = amr[p];
#pragma unroll
        for (int j = 0; j < 4; ++j) {
          bv[j] = (short)f2bf(lut[(cr[p][0][j] << 5) + ln31] * am);
          bv[j + 4] = (short)f2bf(lut[(cr[p][1][j] << 5) + ln31] * am);
        }
      } else {
        bv = wreg[p];
      }
      *(s16x8*)(bwp + p * 32 * 128) = bv;
    }
    __syncthreads();

    if (kt + 1 < nkt)
      stage_load<FUSED>(ap0, cp0, wp0, am0, K, kt + 1, ar, cr, wreg, amr);

#pragma unroll
    for (int kk = 0; kk < 2; ++kk) {
      const int qa = (fcolb | (kk << 6)) ^ aswz;
      const int qb = (fcolb | (kk << 6)) ^ bswz;
      s16x8 af[4], bfr[4];
#pragma unroll
      for (int mi = 0; mi < 4; ++mi)
        af[mi] = *(const s16x8*)(asp + mi * 2048 + qa);
#pragma unroll
      for (int ni = 0; ni < 4; ++ni)
        bfr[ni] = *(const s16x8*)(bsp + ni * 2048 + qb);
#pragma unroll
      for (int mi = 0; mi < 4; ++mi)
#pragma unroll
        for (int ni = 0; ni < 4; ++ni)
          acc[mi][ni] = __builtin_amdgcn_mfma_f32_16x16x32_bf16(
              af[mi], bfr[ni], acc[mi][ni], 0, 0, 0);
    }
  }

  const int crow = tm * BM + wr * 64 + ((lane >> 4) << 2);
  const int ccol = tn * BN + wc * 64 + frow;
  float bvv[4];
#pragma unroll
  for (int ni = 0; ni < 4; ++ni) bvv[ni] = BIAS[ccol + ni * 16];
#pragma unroll
  for (int mi = 0; mi < 4; ++mi)
#pragma unroll
    for (int ni = 0; ni < 4; ++ni) {
#pragma unroll
      for (int j = 0; j < 4; ++j) {
        OUT[(size_t)(crow + mi * 16 + j) * N + ccol + ni * 16] =
            acc[mi][ni][j] + bvv[ni];
      }
    }
}

extern "C" void kernel_launch(void* const* d_in, const int* in_sizes, int n_in,
                              void* d_out, int out_size, void* d_ws,
                              size_t ws_size, hipStream_t stream) {
  const float* x = (const float*)d_in[0];
  const int* codes = (const int*)d_in[1];
  const float* absmax = (const float*)d_in[2];
  const float* bias = (const float*)d_in[3];
  float* out = (float*)d_out;

  const int N = in_sizes[3];                    // out features
  const long long nk = (long long)in_sizes[1];  // N*K
  const int K = (int)(nk / N);
  const int M = in_sizes[0] / K;

  const size_t needA = (size_t)M * K * 2;
  const size_t needB = (size_t)N * K * 2;

  const bool big_ok = (ws_size >= needA + needB) && (M % TBM == 0) &&
                      (N % TBN == 0) && (K % TBK == 0) && (K >= 128);

  if (big_ok) {
    u16* xb = (u16*)d_ws;
    u16* wb = (u16*)((char*)d_ws + needA);
    long long nx = (long long)M * K;
    convert_x<<<(int)((nx / 8 + 255) / 256), 256, 0, stream>>>(x, xb, nx);
    dequant_w<<<(int)((nk / 8 + 255) / 256), 256, 0, stream>>>(codes, absmax,
                                                               wb, nk);
    dim3 grid((M / TBM) * (N / TBN)), blk(512);
    gemm8<<<grid, blk, 0, stream>>>(xb, wb, bias, out, M, N, K);
  } else if (ws_size >= needB) {
    u16* wq = (u16*)d_ws;
    dequant_w<<<(int)((nk / 8 + 255) / 256), 256, 0, stream>>>(codes, absmax,
                                                               wq, nk);
    dim3 grid((M / BM) * (N / BN)), blk(256);
    gemm_nf4<false><<<grid, blk, 0, stream>>>(x, codes, wq, absmax, bias, out,
                                              M, N, K);
  } else {
    dim3 grid((M / BM) * (N / BN)), blk(256);
    gemm_nf4<true><<<grid, blk, 0, stream>>>(x, codes, (const u16*)nullptr,
                                             absmax, bias, out, M, N, K);
  }
}

// Round 3
// 292.428 us; speedup vs baseline: 1.4593x; 1.0538x over previous
//
#include <hip/hip_runtime.h>
#include <hip/hip_bf16.h>

typedef float f32x4 __attribute__((ext_vector_type(4)));
typedef short s16x8 __attribute__((ext_vector_type(8)));
typedef int i32x4 __attribute__((ext_vector_type(4)));
typedef unsigned short u16;

__constant__ float NF4_TBL[16] = {
    -1.0f, -0.6961928009986877f, -0.5250730514526367f, -0.39491748809814453f,
    -0.28444138169288635f, -0.18477343022823334f, -0.09105003625154495f, 0.0f,
    0.07958029955625534f, 0.16093020141124725f, 0.24611230194568634f,
    0.33791524171829224f, 0.44070982933044434f, 0.5626170039176941f,
    0.7229568362236023f, 1.0f};

static __device__ __forceinline__ unsigned short f2bf(float f) {
  unsigned u = __builtin_bit_cast(unsigned, f);
  u += 0x7fffu + ((u >> 16) & 1u);  // RNE
  return (unsigned short)(u >> 16);
}

static __device__ __forceinline__ void gload16(const void* g, void* l) {
  __builtin_amdgcn_global_load_lds(
      (const __attribute__((address_space(1))) unsigned*)g,
      (__attribute__((address_space(3))) unsigned*)l, 16, 0, 0);
}

// ---------------- prep pass 1: X fp32 -> bf16 ----------------
__global__ __launch_bounds__(256)
void convert_x(const float* __restrict__ x, u16* __restrict__ xb,
               long long total) {
  long long i = ((long long)blockIdx.x * 256 + threadIdx.x) * 8;
  if (i >= total) return;
  f32x4 a = *(const f32x4*)(x + i);
  f32x4 b = *(const f32x4*)(x + i + 4);
  s16x8 o;
#pragma unroll
  for (int j = 0; j < 4; ++j) {
    o[j] = (short)f2bf(a[j]);
    o[j + 4] = (short)f2bf(b[j]);
  }
  *(s16x8*)(xb + i) = o;
}

// ---------------- prep pass 2: NF4 codes -> bf16 W ----------------
__global__ __launch_bounds__(256)
void dequant_w(const int* __restrict__ codes, const float* __restrict__ absmax,
               u16* __restrict__ wq, long long total) {
  __shared__ float lut[512];
  for (int j = threadIdx.x; j < 512; j += 256) lut[j] = NF4_TBL[j >> 5];
  __syncthreads();
  const int ln31 = threadIdx.x & 31;
  long long e = ((long long)blockIdx.x * 256 + threadIdx.x) * 8;
  if (e >= total) return;
  i32x4 c0 = *(const i32x4*)(codes + e);
  i32x4 c1 = *(const i32x4*)(codes + e + 4);
  float am = absmax[e >> 6];
  s16x8 o;
#pragma unroll
  for (int j = 0; j < 4; ++j) {
    o[j] = (short)f2bf(lut[(c0[j] << 5) + ln31] * am);
    o[j + 4] = (short)f2bf(lut[(c1[j] << 5) + ln31] * am);
  }
  *(s16x8*)(wq + e) = o;
}

// ============ main: 256x256 bf16 GEMM, BK=64, 8-phase schedule ============
// C[M,N] = A[M,K]*B[N,K]^T + bias.  buf0 = even K-tiles, buf1 = odd.
// Per iteration (2 K-tiles, 128 K): 8 phases, each
//   { ds_read operand half -> regs | stage 1 half-tile (2 gload_lds) |
//     barrier; lgkmcnt(0); sched_barrier; setprio(1); 16 MFMA; setprio(0);
//     barrier }
// vmcnt(6) only at phases 4 and 8 (16 loads max in flight; newest 3 stages
// may stay outstanding). LDS st-swizzle: 16B-slot ^= (row&7), applied to the
// pre-swizzled global SOURCE on stage and to the ds_read address (rule #21).
#define VM6() asm volatile("s_waitcnt vmcnt(6)" ::: "memory")
#define VM0() asm volatile("s_waitcnt vmcnt(0)" ::: "memory")
#define SYNC_IN()                                            \
  do {                                                       \
    __builtin_amdgcn_s_barrier();                            \
    asm volatile("s_waitcnt lgkmcnt(0)" ::: "memory");       \
    __builtin_amdgcn_sched_barrier(0);                       \
  } while (0)
#define SYNC_OUT()                                           \
  do {                                                       \
    __builtin_amdgcn_s_barrier();                            \
    __builtin_amdgcn_sched_barrier(0);                       \
  } while (0)

#define MM(BV, MB, NB)                                                     \
  do {                                                                     \
    __builtin_amdgcn_s_setprio(1);                                         \
    _Pragma("unroll") for (int m_ = 0; m_ < 4; ++m_)                       \
    _Pragma("unroll") for (int n_ = 0; n_ < 2; ++n_)                       \
    _Pragma("unroll") for (int k_ = 0; k_ < 2; ++k_)                       \
        acc[(MB) + m_][(NB) + n_] =                                        \
            __builtin_amdgcn_mfma_f32_16x16x32_bf16(                       \
                af[m_][k_], BV[n_][k_], acc[(MB) + m_][(NB) + n_], 0, 0, 0); \
    __builtin_amdgcn_s_setprio(0);                                         \
  } while (0)

__global__ __launch_bounds__(512, 2)
void gemm8p(const u16* __restrict__ A, const u16* __restrict__ B,
            const float* __restrict__ BIAS, float* __restrict__ OUT,
            int M, int N, int K) {
  __shared__ __align__(16) char lds[131072];  // 2 buf x (A 32K + B 32K)

  const int tid = threadIdx.x;
  const int lane = tid & 63;
  const int wid = tid >> 6;
  const int wr = wid >> 2;  // 0..1 : M-half (128 rows)
  const int wc = wid & 3;   // 0..3 : N-quarter (64 cols)

  int nwg = (int)gridDim.x;
  int b = (int)blockIdx.x;
  if ((nwg & 7) == 0) b = (b & 7) * (nwg >> 3) + (b >> 3);  // XCD swizzle
  const int ntm = M / 256;
  const int tn = b / ntm;  // column-major tile order: B-panel L2 reuse
  const int tm = b % ntm;

  const long long K2 = (long long)K * 2;
  // ---- staging source (pre-swizzled 16B slot within 128B K-row) ----
  const int trow = tid >> 3;
  const int scol = ((tid & 7) ^ (trow & 7)) << 4;
  const char* sgA =
      (const char*)A + ((long long)tm * 256 + trow) * K2 + scol;
  const char* sgB = (const char*)B +
                    ((long long)tn * 256 + (tid >> 8) * 64 + (trow & 31)) * K2 +
                    scol;
  const int sldso = tid * 16;

  // ---- fragment read addressing ----
  const int frow = lane & 15;
  const int sw = (frow & 7) << 4;
  const int koff0 = (((lane >> 4) << 4)) ^ sw;  // kk=0 slot
  const int koff1 = koff0 ^ 64;                 // kk=1 (bit6 disjoint)
  const int aro = (wr * 64 + frow) * 128;           // within A half
  const int bro = (wc * 32 + frow) * 128 + 32768;   // within buf, B region

  // stage one half-tile (2 x gload16). A half h: global rows h*64+r, 128+h*64+r
  auto stA = [&](int kt, int buf, int h) {
    char* d = lds + buf * 65536 + h * 16384 + sldso;
    const char* s = sgA + (long long)h * 64 * K2 + (long long)kt * 128;
    gload16(s, d);
    gload16(s + 128 * K2, d + 8192);
  };
  // B half h: global rows h*32 + {0-31,64-95} (+128 for q=1)
  auto stB = [&](int kt, int buf, int h) {
    char* d = lds + buf * 65536 + 32768 + h * 16384 + sldso;
    const char* s = sgB + (long long)h * 32 * K2 + (long long)kt * 128;
    gload16(s, d);
    gload16(s + 128 * K2, d + 8192);
  };

  s16x8 af[4][2], bva[2][2], bvb[2][2];
  auto rdA = [&](int buf, int h) {
    const char* p = lds + buf * 65536 + h * 16384 + aro;
#pragma unroll
    for (int m_ = 0; m_ < 4; ++m_) {
      af[m_][0] = *(const s16x8*)(p + m_ * 2048 + koff0);
      af[m_][1] = *(const s16x8*)(p + m_ * 2048 + koff1);
    }
  };
  auto rdB = [&](int buf, int h, s16x8(&bv)[2][2]) {
    const char* p = lds + buf * 65536 + h * 16384 + bro;
#pragma unroll
    for (int n_ = 0; n_ < 2; ++n_) {
      bv[n_][0] = *(const s16x8*)(p + n_ * 2048 + koff0);
      bv[n_][1] = *(const s16x8*)(p + n_ * 2048 + koff1);
    }
  };

  f32x4 acc[8][4];
#pragma unroll
  for (int i = 0; i < 8; ++i)
#pragma unroll
    for (int j = 0; j < 4; ++j) {
      f32x4 z = {0.f, 0.f, 0.f, 0.f};
      acc[i][j] = z;
    }

  const int nkt = K / 64;
  const int nit = nkt / 2;

  // prologue: buf0 <- kt0 (full), buf1 <- kt1 (all but A-half-b)
  stB(0, 0, 0);
  stA(0, 0, 0);
  stB(0, 0, 1);
  stA(0, 0, 1);
  stB(1, 1, 0);
  stA(1, 1, 0);
  stB(1, 1, 1);
  VM6();  // buf0 complete; buf1's 3 stages may stay in flight
  __builtin_amdgcn_s_barrier();

  for (int it = 0; it < nit; ++it) {
    const int kt = 2 * it;
    const bool full = (it + 1 < nit);
    __builtin_amdgcn_sched_barrier(0);
    // ---- p1: quadrant (mi0-3, ni0-1) of kt ----
    rdA(0, 0);
    rdB(0, 0, bva);
    stA(kt + 1, 1, 1);  // buf1.A-b <- kt+1 (read at p7)
    SYNC_IN();
    MM(bva, 0, 0);
    SYNC_OUT();
    // ---- p2: (mi0-3, ni2-3) ----
    rdB(0, 1, bvb);
    if (full) stB(kt + 2, 0, 0);
    SYNC_IN();
    MM(bvb, 0, 2);
    SYNC_OUT();
    // ---- p3: (mi4-7, ni2-3) ----
    rdA(0, 1);
    if (full) stA(kt + 2, 0, 0);
    SYNC_IN();
    MM(bvb, 4, 2);
    SYNC_OUT();
    // ---- p4: (mi4-7, ni0-1); vmcnt gate for p5-p7 ----
    if (full) {
      stB(kt + 2, 0, 1);
      VM6();
    } else {
      VM0();
    }
    SYNC_IN();
    MM(bva, 4, 0);
    SYNC_OUT();
    // ---- p5: quadrant (mi0-3, ni0-1) of kt+1 (buf1) ----
    rdA(1, 0);
    rdB(1, 0, bva);
    if (full) stA(kt + 2, 0, 1);
    SYNC_IN();
    MM(bva, 0, 0);
    SYNC_OUT();
    // ---- p6 ----
    rdB(1, 1, bvb);
    if (full) stB(kt + 3, 1, 0);
    SYNC_IN();
    MM(bvb, 0, 2);
    SYNC_OUT();
    // ---- p7 ----
    rdA(1, 1);
    if (full) stA(kt + 3, 1, 0);
    SYNC_IN();
    MM(bvb, 4, 2);
    SYNC_OUT();
    // ---- p8: vmcnt gate for next p1-p4 ----
    if (full) {
      stB(kt + 3, 1, 1);
      VM6();
    }
    SYNC_IN();
    MM(bva, 4, 0);
    SYNC_OUT();
  }

  // epilogue: D row = (lane>>4)*4 + j (M), col = lane&15 (N)
  const int orow0 = tm * 256 + wr * 128 + ((lane >> 4) << 2);
  const int ocol0 = tn * 256 + wc * 64 + frow;
  float bv[4];
#pragma unroll
  for (int n_ = 0; n_ < 4; ++n_) bv[n_] = BIAS[ocol0 + n_ * 16];
#pragma unroll
  for (int m_ = 0; m_ < 8; ++m_)
#pragma unroll
    for (int n_ = 0; n_ < 4; ++n_) {
#pragma unroll
      for (int j = 0; j < 4; ++j) {
        OUT[(long long)(orow0 + m_ * 16 + j) * N + ocol0 + n_ * 16] =
            acc[m_][n_][j] + bv[n_];
      }
    }
}

// ---------------- fallback: 128x128 reg-staged kernel ----------------
#define BM 128
#define BN 128
#define BK 64

template <bool FUSED>
static __device__ __forceinline__ void stage_load(
    const float* __restrict__ ap0, const int* __restrict__ cp0,
    const u16* __restrict__ wp0, const float* __restrict__ am0, int K, int kt,
    f32x4 (&ar)[4][2], i32x4 (&cr)[4][2], s16x8 (&wreg)[4], float (&amr)[4]) {
  const size_t ko = (size_t)kt * BK;
#pragma unroll
  for (int p = 0; p < 4; ++p) {
    const float* ap = ap0 + (size_t)(p * 32) * K + ko;
    ar[p][0] = *(const f32x4*)ap;
    ar[p][1] = *(const f32x4*)(ap + 4);
    if constexpr (FUSED) {
      const int* cp = cp0 + (size_t)(p * 32) * K + ko;
      cr[p][0] = *(const i32x4*)cp;
      cr[p][1] = *(const i32x4*)(cp + 4);
      amr[p] = am0[p * 32 * (K >> 6) + kt];
    } else {
      wreg[p] = *(const s16x8*)(wp0 + (size_t)(p * 32) * K + ko);
    }
  }
}

template <bool FUSED>
__global__ __launch_bounds__(256, 2)
void gemm_nf4(const float* __restrict__ X, const int* __restrict__ CODES,
              const u16* __restrict__ WQ, const float* __restrict__ AMAX,
              const float* __restrict__ BIAS, float* __restrict__ OUT,
              int M, int N, int K) {
  __shared__ short As[BM * BK];
  __shared__ short Bs[BN * BK];
  __shared__ float lut[512];

  const int tid = threadIdx.x;
  const int lane = tid & 63;
  const int wid = tid >> 6;

  if constexpr (FUSED) {
#pragma unroll
    for (int j = 0; j < 2; ++j) {
      int idx = tid + j * 256;
      lut[idx] = NF4_TBL[idx >> 5];
    }
  }

  int nwg = (int)gridDim.x;
  int b = (int)blockIdx.x;
  if ((nwg & 7) == 0) b = (b & 7) * (nwg >> 3) + (b >> 3);
  const int ntn = N / BN;
  const int tm = b / ntn;
  const int tn = b % ntn;

  const int srow = tid >> 3;
  const int scol = (tid & 7) * 8;
  const int ln31 = tid & 31;
  const int swz_w = (srow & 7) << 4;

  const float* ap0 = X + (size_t)(tm * BM + srow) * K + scol;
  const int* cp0 = CODES + (size_t)(tn * BN + srow) * K + scol;
  const u16* wp0 = WQ + (size_t)(tn * BN + srow) * K + scol;
  const float* am0 = AMAX + (size_t)(tn * BN + srow) * (K >> 6);

  f32x4 ar[4][2];
  i32x4 cr[4][2];
  s16x8 wreg[4];
  float amr[4];

  f32x4 acc[4][4];
#pragma unroll
  for (int i = 0; i < 4; ++i)
#pragma unroll
    for (int j = 0; j < 4; ++j) {
      f32x4 z = {0.f, 0.f, 0.f, 0.f};
      acc[i][j] = z;
    }

  const int wr = wid >> 1;
  const int wc = wid & 1;
  const int frow = lane & 15;
  const int fcolb = (lane >> 4) * 16;
  const int arow = wr * 64 + frow;
  const int brow = wc * 64 + frow;
  const int aswz = (arow & 7) << 4;
  const int bswz = (brow & 7) << 4;
  const char* asp = (const char*)As + arow * 128;
  const char* bsp = (const char*)Bs + brow * 128;
  char* awp = (char*)As + srow * 128 + ((scol * 2) ^ swz_w);
  char* bwp = (char*)Bs + srow * 128 + ((scol * 2) ^ swz_w);

  const int nkt = K / BK;
  stage_load<FUSED>(ap0, cp0, wp0, am0, K, 0, ar, cr, wreg, amr);

  for (int kt = 0; kt < nkt; ++kt) {
    __syncthreads();
#pragma unroll
    for (int p = 0; p < 4; ++p) {
      s16x8 av;
#pragma unroll
      for (int j = 0; j < 4; ++j) {
        av[j] = (short)f2bf(ar[p][0][j]);
        av[j + 4] = (short)f2bf(ar[p][1][j]);
      }
      *(s16x8*)(awp + p * 32 * 128) = av;
      s16x8 bv;
      if constexpr (FUSED) {
        float am = amr[p];
#pragma unroll
        for (int j = 0; j < 4; ++j) {
          bv[j] = (short)f2bf(lut[(cr[p][0][j] << 5) + ln31] * am);
          bv[j + 4] = (short)f2bf(lut[(cr[p][1][j] << 5) + ln31] * am);
        }
      } else {
        bv = wreg[p];
      }
      *(s16x8*)(bwp + p * 32 * 128) = bv;
    }
    __syncthreads();

    if (kt + 1 < nkt)
      stage_load<FUSED>(ap0, cp0, wp0, am0, K, kt + 1, ar, cr, wreg, amr);

#pragma unroll
    for (int kk = 0; kk < 2; ++kk) {
      const int qa = (fcolb | (kk << 6)) ^ aswz;
      const int qb = (fcolb | (kk << 6)) ^ bswz;
      s16x8 afr[4], bfr[4];
#pragma unroll
      for (int mi = 0; mi < 4; ++mi)
        afr[mi] = *(const s16x8*)(asp + mi * 2048 + qa);
#pragma unroll
      for (int ni = 0; ni < 4; ++ni)
        bfr[ni] = *(const s16x8*)(bsp + ni * 2048 + qb);
#pragma unroll
      for (int mi = 0; mi < 4; ++mi)
#pragma unroll
        for (int ni = 0; ni < 4; ++ni)
          acc[mi][ni] = __builtin_amdgcn_mfma_f32_16x16x32_bf16(
              afr[mi], bfr[ni], acc[mi][ni], 0, 0, 0);
    }
  }

  const int crow = tm * BM + wr * 64 + ((lane >> 4) << 2);
  const int ccol = tn * BN + wc * 64 + frow;
  float bvv[4];
#pragma unroll
  for (int ni = 0; ni < 4; ++ni) bvv[ni] = BIAS[ccol + ni * 16];
#pragma unroll
  for (int mi = 0; mi < 4; ++mi)
#pragma unroll
    for (int ni = 0; ni < 4; ++ni) {
#pragma unroll
      for (int j = 0; j < 4; ++j) {
        OUT[(size_t)(crow + mi * 16 + j) * N + ccol + ni * 16] =
            acc[mi][ni][j] + bvv[ni];
      }
    }
}

extern "C" void kernel_launch(void* const* d_in, const int* in_sizes, int n_in,
                              void* d_out, int out_size, void* d_ws,
                              size_t ws_size, hipStream_t stream) {
  const float* x = (const float*)d_in[0];
  const int* codes = (const int*)d_in[1];
  const float* absmax = (const float*)d_in[2];
  const float* bias = (const float*)d_in[3];
  float* out = (float*)d_out;

  const int N = in_sizes[3];                    // out features
  const long long nk = (long long)in_sizes[1];  // N*K
  const int K = (int)(nk / N);
  const int M = in_sizes[0] / K;

  const size_t needA = (size_t)M * K * 2;
  const size_t needB = (size_t)N * K * 2;

  const bool big_ok = (ws_size >= needA + needB) && (M % 256 == 0) &&
                      (N % 256 == 0) && (K % 128 == 0) && (K >= 512);

  if (big_ok) {
    u16* xb = (u16*)d_ws;
    u16* wb = (u16*)((char*)d_ws + needA);
    long long nx = (long long)M * K;
    convert_x<<<(int)((nx / 8 + 255) / 256), 256, 0, stream>>>(x, xb, nx);
    dequant_w<<<(int)((nk / 8 + 255) / 256), 256, 0, stream>>>(codes, absmax,
                                                               wb, nk);
    dim3 grid((M / 256) * (N / 256)), blk(512);
    gemm8p<<<grid, blk, 0, stream>>>(xb, wb, bias, out, M, N, K);
  } else if (ws_size >= needB) {
    u16* wq = (u16*)d_ws;
    dequant_w<<<(int)((nk / 8 + 255) / 256), 256, 0, stream>>>(codes, absmax,
                                                               wq, nk);
    dim3 grid((M / BM) * (N / BN)), blk(256);
    gemm_nf4<false><<<grid, blk, 0, stream>>>(x, codes, wq, absmax, bias, out,
                                              M, N, K);
  } else {
    dim3 grid((M / BM) * (N / BN)), blk(256);
    gemm_nf4<true><<<grid, blk, 0, stream>>>(x, codes, (const u16*)nullptr,
                                             absmax, bias, out, M, N, K);
  }
}